// Round 4
// baseline (3026.900 us; speedup 1.0000x reference)
//
#include <hip/hip_runtime.h>
#include <math.h>

// ---------------------------------------------------------------------------
// GCN: 3x GCNConv(64->64)+ReLU, mean pool (512 graphs), FC(64->8), sigmoid.
// N=100000, E=1250000. CSR-by-dst (packed int2) + gather agg w/ fused
// self-term/bias/relu; register-resident W matmul.
// ---------------------------------------------------------------------------

#define FEAT 64
#define SCAN_BS 1024

// ---- degree / CSR build ----------------------------------------------------

__global__ void k_zero_int(int* __restrict__ p, int n) {
    int i = blockIdx.x * blockDim.x + threadIdx.x;
    if (i < n) p[i] = 0;
}

__global__ void k_hist(const int* __restrict__ ei, int* __restrict__ deg, int E) {
    int e = blockIdx.x * blockDim.x + threadIdx.x;
    if (e < E) atomicAdd(&deg[ei[E + e]], 1);  // dst = ei[1][e]
}

__global__ void k_dinv(const int* __restrict__ deg, float* __restrict__ dinv, int n) {
    int i = blockIdx.x * blockDim.x + threadIdx.x;
    if (i < n) dinv[i] = rsqrtf((float)deg[i] + 1.0f);  // +1 self-loop
}

__global__ void k_scan1(const int* __restrict__ deg, int* __restrict__ off,
                        int* __restrict__ bsum, int N) {
    __shared__ int sdata[SCAN_BS];
    int tid = threadIdx.x;
    int i = blockIdx.x * SCAN_BS + tid;
    int v = (i < N) ? deg[i] : 0;
    sdata[tid] = v;
    __syncthreads();
    for (int d = 1; d < SCAN_BS; d <<= 1) {
        int t = (tid >= d) ? sdata[tid - d] : 0;
        __syncthreads();
        sdata[tid] += t;
        __syncthreads();
    }
    if (i < N) off[i] = sdata[tid] - v;
    if (tid == SCAN_BS - 1) bsum[blockIdx.x] = sdata[tid];
}

__global__ void k_scan2(int* __restrict__ bsum, int* __restrict__ offN, int nb) {
    __shared__ int sdata[SCAN_BS];
    int tid = threadIdx.x;
    int v = (tid < nb) ? bsum[tid] : 0;
    sdata[tid] = v;
    __syncthreads();
    for (int d = 1; d < SCAN_BS; d <<= 1) {
        int t = (tid >= d) ? sdata[tid - d] : 0;
        __syncthreads();
        sdata[tid] += t;
        __syncthreads();
    }
    if (tid < nb) bsum[tid] = sdata[tid] - v;
    if (tid == nb - 1) *offN = sdata[tid];
}

__global__ void k_scan3(int* __restrict__ off, int* __restrict__ cursor,
                        const int* __restrict__ bsum, int N) {
    int i = blockIdx.x * blockDim.x + threadIdx.x;
    if (i < N) {
        int o = off[i] + bsum[i >> 10];
        off[i] = o;
        cursor[i] = o;
    }
}

__global__ void k_scatter(const int* __restrict__ ei, const float* __restrict__ dinv,
                          int* __restrict__ cursor, int2* __restrict__ csr, int E) {
    int e = blockIdx.x * blockDim.x + threadIdx.x;
    if (e < E) {
        int s = ei[e];
        int d = ei[E + e];
        int pos = atomicAdd(&cursor[d], 1);
        csr[pos] = make_int2(s, __float_as_int(dinv[s] * dinv[d]));
    }
}

// ---- dense: h = X @ W (W column per lane in VGPRs, X via readlane) ---------

__global__ void k_matmul(const float* __restrict__ X, const float* __restrict__ W,
                         float* __restrict__ h, int n) {
    int f = threadIdx.x & 63;
    int w = threadIdx.x >> 6;  // wave 0..3
    float wcol[FEAT];
    #pragma unroll
    for (int k = 0; k < FEAT; ++k) wcol[k] = W[k * FEAT + f];
    int ntiles = (n + 15) >> 4;
    for (int tile = blockIdx.x; tile < ntiles; tile += gridDim.x) {
        int row0 = (tile << 4) + (w << 2);
        bool v0 = row0 < n, v1 = row0 + 1 < n, v2 = row0 + 2 < n, v3 = row0 + 3 < n;
        float x0 = v0 ? X[(size_t)row0 * FEAT + f] : 0.f;
        float x1 = v1 ? X[(size_t)(row0 + 1) * FEAT + f] : 0.f;
        float x2 = v2 ? X[(size_t)(row0 + 2) * FEAT + f] : 0.f;
        float x3 = v3 ? X[(size_t)(row0 + 3) * FEAT + f] : 0.f;
        float a0 = 0.f, a1 = 0.f, a2 = 0.f, a3 = 0.f;
        #pragma unroll
        for (int k = 0; k < FEAT; ++k) {
            float wk = wcol[k];
            a0 += __shfl(x0, k) * wk;
            a1 += __shfl(x1, k) * wk;
            a2 += __shfl(x2, k) * wk;
            a3 += __shfl(x3, k) * wk;
        }
        if (v0) h[(size_t)row0 * FEAT + f] = a0;
        if (v1) h[(size_t)(row0 + 1) * FEAT + f] = a1;
        if (v2) h[(size_t)(row0 + 2) * FEAT + f] = a2;
        if (v3) h[(size_t)(row0 + 3) * FEAT + f] = a3;
    }
}

// ---- aggregation: out = relu(sum_j h[s_j]*c_j + h[node]*dinv^2 + b) --------

__global__ void k_agg(const int* __restrict__ off, const int2* __restrict__ csr,
                      const float* __restrict__ h, const float* __restrict__ dinv,
                      const float* __restrict__ b, float* __restrict__ out, int N) {
    int node = blockIdx.x * (blockDim.x >> 6) + (threadIdx.x >> 6);
    int f = threadIdx.x & 63;
    if (node >= N) return;
    int j = off[node], e1 = off[node + 1];
    float acc = 0.f;
    for (; j + 4 <= e1; j += 4) {
        int2 v0 = csr[j], v1 = csr[j + 1], v2 = csr[j + 2], v3 = csr[j + 3];
        acc += h[(size_t)v0.x * FEAT + f] * __int_as_float(v0.y);
        acc += h[(size_t)v1.x * FEAT + f] * __int_as_float(v1.y);
        acc += h[(size_t)v2.x * FEAT + f] * __int_as_float(v2.y);
        acc += h[(size_t)v3.x * FEAT + f] * __int_as_float(v3.y);
    }
    for (; j < e1; ++j) {
        int2 v = csr[j];
        acc += h[(size_t)v.x * FEAT + f] * __int_as_float(v.y);
    }
    float dv = dinv[node];
    float own = h[(size_t)node * FEAT + f];
    out[(size_t)node * FEAT + f] = fmaxf(acc + own * dv * dv + b[f], 0.f);
}

// ---- pooling + FC ----------------------------------------------------------

__global__ void k_zero_f(float* __restrict__ p, int n) {
    int i = blockIdx.x * blockDim.x + threadIdx.x;
    if (i < n) p[i] = 0.f;
}

#define PCH 64
__global__ void k_pool(const float* __restrict__ h, const int* __restrict__ batch,
                       float* __restrict__ pooled, float* __restrict__ cnt, int N) {
    int wave = blockIdx.x * (blockDim.x >> 6) + (threadIdx.x >> 6);
    int f = threadIdx.x & 63;
    int start = wave * PCH;
    if (start >= N) return;
    int end = start + PCH; if (end > N) end = N;
    int cur = batch[start];
    float acc = 0.f;
    int nl = 0;
    for (int i = start; i < end; ++i) {
        int g = batch[i];
        if (g != cur) {
            atomicAdd(&pooled[(size_t)cur * FEAT + f], acc);
            if (f == 0) atomicAdd(&cnt[cur], (float)nl);
            cur = g; acc = 0.f; nl = 0;
        }
        acc += h[(size_t)i * FEAT + f];
        nl++;
    }
    atomicAdd(&pooled[(size_t)cur * FEAT + f], acc);
    if (f == 0) atomicAdd(&cnt[cur], (float)nl);
}

__global__ void k_fc_sigmoid(const float* __restrict__ pooled, const float* __restrict__ cnt,
                             const float* __restrict__ Wfc, const float* __restrict__ bfc,
                             float* __restrict__ out, int G) {
    __shared__ float P[FEAT];
    int g = blockIdx.x;
    int t = threadIdx.x;
    float c = fmaxf(cnt[g], 1.0f);
    P[t] = pooled[(size_t)g * FEAT + t] / c;
    __syncthreads();
    if (t < 8) {
        float acc = bfc[t];
        #pragma unroll
        for (int f = 0; f < FEAT; ++f) acc += P[f] * Wfc[f * 8 + t];
        out[(size_t)g * 8 + t] = 1.f / (1.f + expf(-acc));
    }
}

// ---------------------------------------------------------------------------

extern "C" void kernel_launch(void* const* d_in, const int* in_sizes, int n_in,
                              void* d_out, int out_size, void* d_ws, size_t ws_size,
                              hipStream_t stream) {
    const float* x    = (const float*)d_in[0];
    const int*   ei   = (const int*)d_in[1];
    const int*   batch= (const int*)d_in[2];
    const float* W0   = (const float*)d_in[3];
    const float* b0   = (const float*)d_in[4];
    const float* W1   = (const float*)d_in[5];
    const float* b1   = (const float*)d_in[6];
    const float* W2   = (const float*)d_in[7];
    const float* b2   = (const float*)d_in[8];
    const float* Wfc  = (const float*)d_in[9];
    const float* bfc  = (const float*)d_in[10];
    float* out = (float*)d_out;

    const int N = in_sizes[0] / FEAT;   // 100000
    const int E = in_sizes[1] / 2;      // 1250000
    const int G = out_size / 8;         // 512
    const int NB = (N + SCAN_BS - 1) / SCAN_BS;

    // ws layout: csr first (16B aligned), then floats/ints
    int2*  csr      = (int2*)d_ws;
    float* bufA     = (float*)(csr + E);
    float* bufB     = bufA + (size_t)N * FEAT;
    float* htmp     = bufB + (size_t)N * FEAT;
    float* dinv     = htmp + (size_t)N * FEAT;
    float* pooled   = dinv + N;
    float* cnt      = pooled + (size_t)G * FEAT;
    int*   deg_i    = (int*)(cnt + G);
    int*   off      = deg_i + N;
    int*   cursor   = off + (N + 1);
    int*   bsum     = cursor + N;

    const int TB = 256;
    dim3 blk(TB);
    dim3 gN((N + TB - 1) / TB);
    dim3 gE((E + TB - 1) / TB);

    // --- CSR build (once per call) ---
    k_zero_int<<<gN, blk, 0, stream>>>(deg_i, N);
    k_hist<<<gE, blk, 0, stream>>>(ei, deg_i, E);
    k_dinv<<<gN, blk, 0, stream>>>(deg_i, dinv, N);
    k_scan1<<<dim3(NB), dim3(SCAN_BS), 0, stream>>>(deg_i, off, bsum, N);
    k_scan2<<<dim3(1), dim3(SCAN_BS), 0, stream>>>(bsum, off + N, NB);
    k_scan3<<<gN, blk, 0, stream>>>(off, cursor, bsum, N);
    k_scatter<<<gE, blk, 0, stream>>>(ei, dinv, cursor, csr, E);

    dim3 gAgg((N + 3) / 4);
    dim3 gMM(1024);

    // --- layer 0 ---
    k_matmul<<<gMM, blk, 0, stream>>>(x, W0, htmp, N);
    k_agg<<<gAgg, blk, 0, stream>>>(off, csr, htmp, dinv, b0, bufA, N);
    // --- layer 1 ---
    k_matmul<<<gMM, blk, 0, stream>>>(bufA, W1, htmp, N);
    k_agg<<<gAgg, blk, 0, stream>>>(off, csr, htmp, dinv, b1, bufB, N);
    // --- layer 2 ---
    k_matmul<<<gMM, blk, 0, stream>>>(bufB, W2, htmp, N);
    k_agg<<<gAgg, blk, 0, stream>>>(off, csr, htmp, dinv, b2, bufA, N);

    // --- pooling + FC + sigmoid ---
    k_zero_f<<<dim3((G * (FEAT + 1) + TB - 1) / TB), blk, 0, stream>>>(pooled, G * (FEAT + 1));
    k_pool<<<dim3(((N + PCH - 1) / PCH + 3) / 4), blk, 0, stream>>>(bufA, batch, pooled, cnt, N);
    k_fc_sigmoid<<<dim3(G), dim3(FEAT), 0, stream>>>(pooled, cnt, Wfc, bfc, out, G);
}

// Round 5
// 514.283 us; speedup vs baseline: 5.8857x; 5.8857x over previous
//
#include <hip/hip_runtime.h>
#include <math.h>

// ---------------------------------------------------------------------------
// GCN: 3x GCNConv(64->64)+ReLU, mean pool (512 graphs), FC(64->8), sigmoid.
// N=100000, E=1250000. CSR-by-dst (packed int2) + gather agg w/ fused
// self-term/bias/relu; LDS-staged matmul (4 rows/thread).
// ---------------------------------------------------------------------------

#define FEAT 64
#define SCAN_BS 1024

// ---- degree / CSR build ----------------------------------------------------

__global__ void k_zero_int(int* __restrict__ p, int n) {
    int i = blockIdx.x * blockDim.x + threadIdx.x;
    if (i < n) p[i] = 0;
}

__global__ void k_hist(const int* __restrict__ ei, int* __restrict__ deg, int E) {
    int e = blockIdx.x * blockDim.x + threadIdx.x;
    if (e < E) atomicAdd(&deg[ei[E + e]], 1);  // dst = ei[1][e]
}

__global__ void k_dinv(const int* __restrict__ deg, float* __restrict__ dinv, int n) {
    int i = blockIdx.x * blockDim.x + threadIdx.x;
    if (i < n) dinv[i] = rsqrtf((float)deg[i] + 1.0f);  // +1 self-loop
}

__global__ void k_scan1(const int* __restrict__ deg, int* __restrict__ off,
                        int* __restrict__ bsum, int N) {
    __shared__ int sdata[SCAN_BS];
    int tid = threadIdx.x;
    int i = blockIdx.x * SCAN_BS + tid;
    int v = (i < N) ? deg[i] : 0;
    sdata[tid] = v;
    __syncthreads();
    for (int d = 1; d < SCAN_BS; d <<= 1) {
        int t = (tid >= d) ? sdata[tid - d] : 0;
        __syncthreads();
        sdata[tid] += t;
        __syncthreads();
    }
    if (i < N) off[i] = sdata[tid] - v;
    if (tid == SCAN_BS - 1) bsum[blockIdx.x] = sdata[tid];
}

__global__ void k_scan2(int* __restrict__ bsum, int* __restrict__ offN, int nb) {
    __shared__ int sdata[SCAN_BS];
    int tid = threadIdx.x;
    int v = (tid < nb) ? bsum[tid] : 0;
    sdata[tid] = v;
    __syncthreads();
    for (int d = 1; d < SCAN_BS; d <<= 1) {
        int t = (tid >= d) ? sdata[tid - d] : 0;
        __syncthreads();
        sdata[tid] += t;
        __syncthreads();
    }
    if (tid < nb) bsum[tid] = sdata[tid] - v;
    if (tid == nb - 1) *offN = sdata[tid];
}

__global__ void k_scan3(int* __restrict__ off, int* __restrict__ cursor,
                        const int* __restrict__ bsum, int N) {
    int i = blockIdx.x * blockDim.x + threadIdx.x;
    if (i < N) {
        int o = off[i] + bsum[i >> 10];
        off[i] = o;
        cursor[i] = o;
    }
}

__global__ void k_scatter(const int* __restrict__ ei, const float* __restrict__ dinv,
                          int* __restrict__ cursor, int2* __restrict__ csr, int E) {
    int e = blockIdx.x * blockDim.x + threadIdx.x;
    if (e < E) {
        int s = ei[e];
        int d = ei[E + e];
        int pos = atomicAdd(&cursor[d], 1);
        csr[pos] = make_int2(s, __float_as_int(dinv[s] * dinv[d]));
    }
}

// ---- dense: h = X @ W (LDS-staged, 4 rows per thread) ----------------------

__global__ void k_matmul(const float* __restrict__ X, const float* __restrict__ W,
                         float* __restrict__ h, int n) {
    __shared__ float Ws[FEAT][FEAT];   // 16 KB
    __shared__ float Xs[16][FEAT];     // 4 KB
    int f = threadIdx.x & 63;
    int w = threadIdx.x >> 6;          // wave 0..3
    for (int i = threadIdx.x; i < FEAT * FEAT; i += 256) Ws[i >> 6][i & 63] = W[i];
    int ntiles = (n + 15) >> 4;
    for (int tile = blockIdx.x; tile < ntiles; tile += gridDim.x) {
        int rowbase = tile << 4;
        __syncthreads();   // protect Ws (iter 0) / Xs reuse
        #pragma unroll
        for (int r = 0; r < 4; ++r) {
            int row = rowbase + w * 4 + r;
            Xs[w * 4 + r][f] = (row < n) ? X[(size_t)row * FEAT + f] : 0.f;
        }
        __syncthreads();
        float a0 = 0.f, a1 = 0.f, a2 = 0.f, a3 = 0.f;
        #pragma unroll
        for (int k = 0; k < FEAT; ++k) {
            float wk = Ws[k][f];
            a0 += Xs[w * 4 + 0][k] * wk;
            a1 += Xs[w * 4 + 1][k] * wk;
            a2 += Xs[w * 4 + 2][k] * wk;
            a3 += Xs[w * 4 + 3][k] * wk;
        }
        int row0 = rowbase + w * 4;
        if (row0 + 3 < n) {
            h[(size_t)(row0 + 0) * FEAT + f] = a0;
            h[(size_t)(row0 + 1) * FEAT + f] = a1;
            h[(size_t)(row0 + 2) * FEAT + f] = a2;
            h[(size_t)(row0 + 3) * FEAT + f] = a3;
        } else {
            if (row0 + 0 < n) h[(size_t)(row0 + 0) * FEAT + f] = a0;
            if (row0 + 1 < n) h[(size_t)(row0 + 1) * FEAT + f] = a1;
            if (row0 + 2 < n) h[(size_t)(row0 + 2) * FEAT + f] = a2;
        }
    }
}

// ---- aggregation: out = relu(sum_j h[s_j]*c_j + h[node]*dinv^2 + b) --------

__global__ void k_agg(const int* __restrict__ off, const int2* __restrict__ csr,
                      const float* __restrict__ h, const float* __restrict__ dinv,
                      const float* __restrict__ b, float* __restrict__ out, int N) {
    int node = blockIdx.x * (blockDim.x >> 6) + (threadIdx.x >> 6);
    int f = threadIdx.x & 63;
    if (node >= N) return;
    int j = off[node], e1 = off[node + 1];
    float acc = 0.f;
    for (; j + 4 <= e1; j += 4) {
        int2 v0 = csr[j], v1 = csr[j + 1], v2 = csr[j + 2], v3 = csr[j + 3];
        acc += h[(size_t)v0.x * FEAT + f] * __int_as_float(v0.y);
        acc += h[(size_t)v1.x * FEAT + f] * __int_as_float(v1.y);
        acc += h[(size_t)v2.x * FEAT + f] * __int_as_float(v2.y);
        acc += h[(size_t)v3.x * FEAT + f] * __int_as_float(v3.y);
    }
    for (; j < e1; ++j) {
        int2 v = csr[j];
        acc += h[(size_t)v.x * FEAT + f] * __int_as_float(v.y);
    }
    float dv = dinv[node];
    float own = h[(size_t)node * FEAT + f];
    out[(size_t)node * FEAT + f] = fmaxf(acc + own * dv * dv + b[f], 0.f);
}

// ---- pooling + FC ----------------------------------------------------------

__global__ void k_zero_f(float* __restrict__ p, int n) {
    int i = blockIdx.x * blockDim.x + threadIdx.x;
    if (i < n) p[i] = 0.f;
}

#define PCH 64
__global__ void k_pool(const float* __restrict__ h, const int* __restrict__ batch,
                       float* __restrict__ pooled, float* __restrict__ cnt, int N) {
    int wave = blockIdx.x * (blockDim.x >> 6) + (threadIdx.x >> 6);
    int f = threadIdx.x & 63;
    int start = wave * PCH;
    if (start >= N) return;
    int end = start + PCH; if (end > N) end = N;
    int cur = batch[start];
    float acc = 0.f;
    int nl = 0;
    for (int i = start; i < end; ++i) {
        int g = batch[i];
        if (g != cur) {
            atomicAdd(&pooled[(size_t)cur * FEAT + f], acc);
            if (f == 0) atomicAdd(&cnt[cur], (float)nl);
            cur = g; acc = 0.f; nl = 0;
        }
        acc += h[(size_t)i * FEAT + f];
        nl++;
    }
    atomicAdd(&pooled[(size_t)cur * FEAT + f], acc);
    if (f == 0) atomicAdd(&cnt[cur], (float)nl);
}

__global__ void k_fc_sigmoid(const float* __restrict__ pooled, const float* __restrict__ cnt,
                             const float* __restrict__ Wfc, const float* __restrict__ bfc,
                             float* __restrict__ out, int G) {
    __shared__ float P[FEAT];
    int g = blockIdx.x;
    int t = threadIdx.x;
    float c = fmaxf(cnt[g], 1.0f);
    P[t] = pooled[(size_t)g * FEAT + t] / c;
    __syncthreads();
    if (t < 8) {
        float acc = bfc[t];
        #pragma unroll
        for (int f = 0; f < FEAT; ++f) acc += P[f] * Wfc[f * 8 + t];
        out[(size_t)g * 8 + t] = 1.f / (1.f + expf(-acc));
    }
}

// ---------------------------------------------------------------------------

extern "C" void kernel_launch(void* const* d_in, const int* in_sizes, int n_in,
                              void* d_out, int out_size, void* d_ws, size_t ws_size,
                              hipStream_t stream) {
    const float* x    = (const float*)d_in[0];
    const int*   ei   = (const int*)d_in[1];
    const int*   batch= (const int*)d_in[2];
    const float* W0   = (const float*)d_in[3];
    const float* b0   = (const float*)d_in[4];
    const float* W1   = (const float*)d_in[5];
    const float* b1   = (const float*)d_in[6];
    const float* W2   = (const float*)d_in[7];
    const float* b2   = (const float*)d_in[8];
    const float* Wfc  = (const float*)d_in[9];
    const float* bfc  = (const float*)d_in[10];
    float* out = (float*)d_out;

    const int N = in_sizes[0] / FEAT;   // 100000
    const int E = in_sizes[1] / 2;      // 1250000
    const int G = out_size / 8;         // 512
    const int NB = (N + SCAN_BS - 1) / SCAN_BS;

    int2*  csr      = (int2*)d_ws;
    float* bufA     = (float*)(csr + E);
    float* bufB     = bufA + (size_t)N * FEAT;
    float* htmp     = bufB + (size_t)N * FEAT;
    float* dinv     = htmp + (size_t)N * FEAT;
    float* pooled   = dinv + N;
    float* cnt      = pooled + (size_t)G * FEAT;
    int*   deg_i    = (int*)(cnt + G);
    int*   off      = deg_i + N;
    int*   cursor   = off + (N + 1);
    int*   bsum     = cursor + N;

    const int TB = 256;
    dim3 blk(TB);
    dim3 gN((N + TB - 1) / TB);
    dim3 gE((E + TB - 1) / TB);

    // --- CSR build (once per call) ---
    k_zero_int<<<gN, blk, 0, stream>>>(deg_i, N);
    k_hist<<<gE, blk, 0, stream>>>(ei, deg_i, E);
    k_dinv<<<gN, blk, 0, stream>>>(deg_i, dinv, N);
    k_scan1<<<dim3(NB), dim3(SCAN_BS), 0, stream>>>(deg_i, off, bsum, N);
    k_scan2<<<dim3(1), dim3(SCAN_BS), 0, stream>>>(bsum, off + N, NB);
    k_scan3<<<gN, blk, 0, stream>>>(off, cursor, bsum, N);
    k_scatter<<<gE, blk, 0, stream>>>(ei, dinv, cursor, csr, E);

    dim3 gAgg((N + 3) / 4);
    dim3 gMM(2048);

    // --- layer 0 ---
    k_matmul<<<gMM, blk, 0, stream>>>(x, W0, htmp, N);
    k_agg<<<gAgg, blk, 0, stream>>>(off, csr, htmp, dinv, b0, bufA, N);
    // --- layer 1 ---
    k_matmul<<<gMM, blk, 0, stream>>>(bufA, W1, htmp, N);
    k_agg<<<gAgg, blk, 0, stream>>>(off, csr, htmp, dinv, b1, bufB, N);
    // --- layer 2 ---
    k_matmul<<<gMM, blk, 0, stream>>>(bufB, W2, htmp, N);
    k_agg<<<gAgg, blk, 0, stream>>>(off, csr, htmp, dinv, b2, bufA, N);

    // --- pooling + FC + sigmoid ---
    k_zero_f<<<dim3((G * (FEAT + 1) + TB - 1) / TB), blk, 0, stream>>>(pooled, G * (FEAT + 1));
    k_pool<<<dim3(((N + PCH - 1) / PCH + 3) / 4), blk, 0, stream>>>(bufA, batch, pooled, cnt, N);
    k_fc_sigmoid<<<dim3(G), dim3(FEAT), 0, stream>>>(pooled, cnt, Wfc, bfc, out, G);
}